// Round 4
// baseline (1214.758 us; speedup 1.0000x reference)
//
#include <hip/hip_runtime.h>
#include <cstddef>

// Swin shifted-window block, bf16-MFMA version, round 6.
// Changes vs round 5 (all in mfma_gemm; other kernels untouched):
//  - LDS-staged coalesced epilogue: after the K-loop, the 32 KB staging
//    LDS is reused to round-trip the 128x128 f32 acc tile (two 64x128
//    passes, XOR-16B swizzle for conflict-floor LDS access). Stores then
//    go out row-major: each thread owns 32 contiguous cols of one row ->
//    float4/uint4 ops, 128B-granule transactions (was 32-64B scattered
//    fragment-layout scalar stores / RMW chains). MODE-1 row remap
//    computed once per row instead of per element.
//  - K-loop staging pipeline (2-deep, vmcnt(4), XOR chunk swizzle)
//    unchanged from round 5 (verified: bank conflicts 0).
//
// ws layout (bytes):
//   [0,           50331648)   wsA   : LN1 out / LN2 out (bf16)
//   [50331648,   100663296)   wsAO  : attn out / z1 (bf16)
//   [100663296,  150994944)   wsQ   : qkv chunk / z2 (bf16)
//   [150994944,  154533888)   wbf   : bf16 weights
//   [154533888,  154589184)   dwt   : fp32 dw weights [9][1536]
// peak ~147.4 MiB.

#define CCH 384
#define HIDCH 1536

typedef __attribute__((ext_vector_type(8))) short short8;
typedef __attribute__((ext_vector_type(4))) float f32x4;

__device__ __forceinline__ float gelu_exact(float v) {
  return 0.5f * v * (1.0f + erff(v * 0.70710678118654752440f));
}
__device__ __forceinline__ unsigned short f2bf(float f) {
  unsigned u = __builtin_bit_cast(unsigned, f);
  u = (u + 0x7FFF + ((u >> 16) & 1)) >> 16;
  return (unsigned short)u;
}
__device__ __forceinline__ float bf2f(unsigned short s) {
  return __builtin_bit_cast(float, (unsigned)s << 16);
}
__device__ __forceinline__ int region_label(int p) {
  return (p < 56) ? 0 : ((p < 60) ? 1 : 2);
}

// async global->LDS, 16B per lane. LDS dest = wave-uniform base + lane*16.
__device__ __forceinline__ void gl_lds16(const void* g, void* l) {
  __builtin_amdgcn_global_load_lds(
      (const __attribute__((address_space(1))) unsigned int*)g,
      (__attribute__((address_space(3))) unsigned int*)l, 16, 0, 0);
}

// ---------------------------------------------------------------------------
// Weight prep: fp32->bf16 for qkv/proj/fc1/fc2, plus dw transpose to
// dwt[tap*1536 + c] = dw_w[c*9 + tap] (fp32).
// ---------------------------------------------------------------------------
__global__ __launch_bounds__(256) void convw_kernel(
    const float* __restrict__ a, const float* __restrict__ b,
    const float* __restrict__ c, const float* __restrict__ d,
    const float* __restrict__ dww, unsigned short* __restrict__ o,
    float* __restrict__ dwt) {
  const int i = blockIdx.x * 256 + threadIdx.x;
  // 442368 + 147456 + 589824 + 589824 = 1769472 bf16 weights, then 13824 dwt
  if (i < 1769472) {
    float v;
    if (i < 442368) v = a[i];
    else if (i < 589824) v = b[i - 442368];
    else if (i < 1179648) v = c[i - 589824];
    else v = d[i - 1179648];
    o[i] = f2bf(v);
  } else if (i < 1769472 + 13824) {
    const int j = i - 1769472;
    const int tap = j / 1536;
    const int ch = j - tap * 1536;
    dwt[j] = dww[ch * 9 + tap];
  }
}

// ---------------------------------------------------------------------------
// LayerNorm -> bf16, one wave per token, 6 channels per lane (float2 x3).
// REMAP=1: out token is windowed/rolled; src via roll(+4).
// ---------------------------------------------------------------------------
template <int REMAP>
__global__ __launch_bounds__(256) void ln_kernel(const float* __restrict__ x,
                                                 const float* __restrict__ g,
                                                 const float* __restrict__ b,
                                                 unsigned short* __restrict__ y) {
  const int t = blockIdx.x * 4 + (threadIdx.x >> 6);
  const int lane = threadIdx.x & 63;
  size_t src;
  if (REMAP) {
    const int widx = t >> 6;
    const int n = t & 63;
    const int bb = widx >> 6;
    const int wh = (widx >> 3) & 7;
    const int ww = widx & 7;
    const int hp = wh * 8 + (n >> 3);
    const int wp = ww * 8 + (n & 7);
    const int hs = (hp + 4) & 63;
    const int wsrc = (wp + 4) & 63;
    src = (size_t)bb * 4096 + hs * 64 + wsrc;
  } else {
    src = (size_t)t;
  }
  const float* xr = x + src * CCH + lane * 6;
  const float2 p0 = *(const float2*)xr;
  const float2 p1 = *(const float2*)(xr + 2);
  const float2 p2 = *(const float2*)(xr + 4);
  float v[6] = {p0.x, p0.y, p1.x, p1.y, p2.x, p2.y};
  float s = 0.f, s2 = 0.f;
#pragma unroll
  for (int j = 0; j < 6; ++j) {
    s += v[j];
    s2 += v[j] * v[j];
  }
#pragma unroll
  for (int o = 1; o < 64; o <<= 1) {
    s += __shfl_xor(s, o);
    s2 += __shfl_xor(s2, o);
  }
  const float mean = s * (1.0f / 384.0f);
  const float var = s2 * (1.0f / 384.0f) - mean * mean;
  const float rstd = rsqrtf(var + 1e-5f);
  const float2 g0 = *(const float2*)(g + lane * 6);
  const float2 g1 = *(const float2*)(g + lane * 6 + 2);
  const float2 g2 = *(const float2*)(g + lane * 6 + 4);
  const float2 b0 = *(const float2*)(b + lane * 6);
  const float2 b1 = *(const float2*)(b + lane * 6 + 2);
  const float2 b2 = *(const float2*)(b + lane * 6 + 4);
  const float gg[6] = {g0.x, g0.y, g1.x, g1.y, g2.x, g2.y};
  const float bv[6] = {b0.x, b0.y, b1.x, b1.y, b2.x, b2.y};
  unsigned pk[3];
#pragma unroll
  for (int i = 0; i < 3; ++i) {
    const float r0 = (v[2 * i] - mean) * rstd * gg[2 * i] + bv[2 * i];
    const float r1 = (v[2 * i + 1] - mean) * rstd * gg[2 * i + 1] + bv[2 * i + 1];
    pk[i] = (unsigned)f2bf(r0) | ((unsigned)f2bf(r1) << 16);
  }
  unsigned* yo = (unsigned*)(y + (size_t)t * CCH + lane * 6);
  yo[0] = pk[0];
  yo[1] = pk[1];
  yo[2] = pk[2];
}

// ---------------------------------------------------------------------------
// bf16 MFMA GEMM: C = A(MxK,bf16) @ W(NxK,bf16)^T + bias.
// 128x128 tile, 256 thr = 4 waves (2x2 of 64x64), 4x4 MFMA 16x16x32 per wave.
// 2-deep pipelined global_load_lds staging (counted vmcnt(4)) + XOR chunk
// swizzle in the K-loop; LDS-staged coalesced epilogue (see header).
// MODE 0: qkv  -> bf16 store (r*N+c)
// MODE 1: proj -> fp32, window-reverse+roll remap, Cout[dst] = Xres[dst]+val
// MODE 2: fc1  -> bf16, gelu(bn(val))
// MODE 3: fc2  -> fp32, Cout[r*N+c] += gelu(bn(val))
// ---------------------------------------------------------------------------
template <int MODE>
__global__ __launch_bounds__(256) void mfma_gemm(
    const unsigned short* __restrict__ A, const unsigned short* __restrict__ W,
    const float* __restrict__ bias, void* __restrict__ CoutV,
    const float* __restrict__ Xres, const float* __restrict__ bng,
    const float* __restrict__ bnb, int N, int K) {
  // unified 32 KB LDS: staging buffers during K-loop, f32 tile in epilogue.
  //  A buf b: smem + b*8192   (rows 0-63 at +wave*1024, rows 64-127 at +4096)
  //  B buf b: smem + 16384 + b*8192
  //  epilogue: 64x128 f32 (XOR-16B swizzled), full 32 KB
  __shared__ __align__(16) char smem[32768];
  const int tid = threadIdx.x;
  const int wave = tid >> 6, lane = tid & 63;
  const int qd = lane >> 4, ln16 = lane & 15;
  const int wm = wave >> 1, wn = wave & 1;
  const int m0 = blockIdx.x * 128;
  const int n0 = blockIdx.y * 128;

  f32x4 acc[4][4];
#pragma unroll
  for (int i = 0; i < 4; ++i)
#pragma unroll
    for (int j = 0; j < 4; ++j) acc[i][j] = (f32x4){0.f, 0.f, 0.f, 0.f};

  const int r = tid >> 2;  // 0..63, row within half-tile
  // swizzled 16B-chunk index: lane's chunk (tid&3) XOR (row>>1)&3
  const int cks = ((tid & 3) ^ ((tid >> 3) & 3)) * 8;

  const unsigned short* gA0 = A + (size_t)(m0 + r) * K + cks;
  const unsigned short* gA1 = A + (size_t)(m0 + 64 + r) * K + cks;
  const unsigned short* gB0 = W + (size_t)(n0 + r) * K + cks;
  const unsigned short* gB1 = W + (size_t)(n0 + 64 + r) * K + cks;
  char* baseA = smem;
  char* baseB = smem + 16384;
  const int wofs = wave * 1024;

  const int nt = K >> 5;
  // prologue: stage tile 0 into buffer 0
  gl_lds16(gA0, baseA + wofs);
  gl_lds16(gA1, baseA + 4096 + wofs);
  gl_lds16(gB0, baseB + wofs);
  gl_lds16(gB1, baseB + 4096 + wofs);

  // fragment-read slot (same XOR involution as staging side)
  const int sA = (qd ^ ((ln16 >> 1) & 3)) * 8;

  int cur = 0;
  for (int t = 0; t < nt; ++t) {
    __builtin_amdgcn_s_barrier();  // all waves done reading buf cur^1
    __builtin_amdgcn_sched_barrier(0);
    if (t + 1 < nt) {
      const int k1 = (t + 1) * 32;
      const int nb = cur ^ 1;
      gl_lds16(gA0 + k1, baseA + nb * 8192 + wofs);
      gl_lds16(gA1 + k1, baseA + nb * 8192 + 4096 + wofs);
      gl_lds16(gB0 + k1, baseB + nb * 8192 + wofs);
      gl_lds16(gB1 + k1, baseB + nb * 8192 + 4096 + wofs);
      asm volatile("s_waitcnt vmcnt(4)" ::: "memory");  // tile t landed
    } else {
      asm volatile("s_waitcnt vmcnt(0)" ::: "memory");
    }
    __builtin_amdgcn_s_barrier();  // every wave's tile-t staging visible
    __builtin_amdgcn_sched_barrier(0);
    short8 af[4], bfr[4];
#pragma unroll
    for (int mt = 0; mt < 4; ++mt)
      af[mt] = *(const short8*)(baseA + cur * 8192 +
                                ((wm * 64 + mt * 16 + ln16) * 32 + sA) * 2);
#pragma unroll
    for (int nt2 = 0; nt2 < 4; ++nt2)
      bfr[nt2] = *(const short8*)(baseB + cur * 8192 +
                                  ((wn * 64 + nt2 * 16 + ln16) * 32 + sA) * 2);
#pragma unroll
    for (int mt = 0; mt < 4; ++mt)
#pragma unroll
      for (int nt2 = 0; nt2 < 4; ++nt2)
        acc[mt][nt2] = __builtin_amdgcn_mfma_f32_16x16x32_bf16(
            af[mt], bfr[nt2], acc[mt][nt2], 0, 0, 0);
    cur ^= 1;
  }

  // ---- LDS-staged coalesced epilogue: two 64x128 passes ----
  const float RSQ = 0.99999500003749969f;  // 1/sqrt(1+1e-5)
  const int erow = tid >> 2;  // 0..63: local row handled by this thread
  const int ecq = tid & 3;    // col quarter (32 cols)
#pragma unroll
  for (int p = 0; p < 2; ++p) {
    __syncthreads();  // staging reads / previous pass's LDS reads done
    if (wm == p) {
#pragma unroll
      for (int mt = 0; mt < 4; ++mt)
#pragma unroll
        for (int nt2 = 0; nt2 < 4; ++nt2)
#pragma unroll
          for (int rg = 0; rg < 4; ++rg) {
            const int rr = mt * 16 + qd * 4 + rg;      // 0..63
            const int cc = wn * 64 + nt2 * 16 + ln16;  // 0..127
            const int byt = ((rr << 9) + (cc << 2)) ^ ((rr & 7) << 4);
            *(float*)(smem + byt) = acc[mt][nt2][rg];
          }
    }
    __syncthreads();
    const int row = m0 + p * 64 + erow;
    const int cb = n0 + ecq * 32;
    f32x4 v[8];
#pragma unroll
    for (int j = 0; j < 8; ++j) {
      const int byt =
          ((erow << 9) + ((ecq * 32 + j * 4) << 2)) ^ ((erow & 7) << 4);
      v[j] = *(const f32x4*)(smem + byt);
    }
    if (MODE == 0) {
      unsigned short* C = (unsigned short*)CoutV;
#pragma unroll
      for (int j2 = 0; j2 < 4; ++j2) {
        unsigned pk[4];
#pragma unroll
        for (int h = 0; h < 2; ++h) {
          const int j = j2 * 2 + h;
          const f32x4 bias4 = *(const f32x4*)&bias[cb + j * 4];
          pk[h * 2] = (unsigned)f2bf(v[j][0] + bias4[0]) |
                      ((unsigned)f2bf(v[j][1] + bias4[1]) << 16);
          pk[h * 2 + 1] = (unsigned)f2bf(v[j][2] + bias4[2]) |
                          ((unsigned)f2bf(v[j][3] + bias4[3]) << 16);
        }
        uint4 st;
        st.x = pk[0]; st.y = pk[1]; st.z = pk[2]; st.w = pk[3];
        *(uint4*)&C[(size_t)row * N + cb + j2 * 8] = st;
      }
    } else if (MODE == 1) {
      const int widx = row >> 6, n = row & 63;
      const int bb_ = widx >> 6, wh = (widx >> 3) & 7, wwi = widx & 7;
      const int hp = wh * 8 + (n >> 3), wp = wwi * 8 + (n & 7);
      const int hh = (hp + 4) & 63, wwp = (wp + 4) & 63;
      const size_t drow = ((size_t)bb_ * 4096 + hh * 64 + wwp) * CCH;
      float* O = (float*)CoutV;
#pragma unroll
      for (int j = 0; j < 8; ++j) {
        const f32x4 bias4 = *(const f32x4*)&bias[cb + j * 4];
        const f32x4 xr = *(const f32x4*)&Xres[drow + cb + j * 4];
        f32x4 o;
#pragma unroll
        for (int e = 0; e < 4; ++e) o[e] = xr[e] + (v[j][e] + bias4[e]);
        *(f32x4*)&O[drow + cb + j * 4] = o;
      }
    } else if (MODE == 2) {
      unsigned short* C = (unsigned short*)CoutV;
#pragma unroll
      for (int j2 = 0; j2 < 4; ++j2) {
        unsigned pk[4];
#pragma unroll
        for (int h = 0; h < 2; ++h) {
          const int j = j2 * 2 + h;
          const f32x4 bias4 = *(const f32x4*)&bias[cb + j * 4];
          const f32x4 g4 = *(const f32x4*)&bng[cb + j * 4];
          const f32x4 bb4 = *(const f32x4*)&bnb[cb + j * 4];
          float ge[4];
#pragma unroll
          for (int e = 0; e < 4; ++e)
            ge[e] = gelu_exact((v[j][e] + bias4[e]) * (g4[e] * RSQ) + bb4[e]);
          pk[h * 2] = (unsigned)f2bf(ge[0]) | ((unsigned)f2bf(ge[1]) << 16);
          pk[h * 2 + 1] =
              (unsigned)f2bf(ge[2]) | ((unsigned)f2bf(ge[3]) << 16);
        }
        uint4 st;
        st.x = pk[0]; st.y = pk[1]; st.z = pk[2]; st.w = pk[3];
        *(uint4*)&C[(size_t)row * N + cb + j2 * 8] = st;
      }
    } else {
      float* O = (float*)CoutV;
#pragma unroll
      for (int j = 0; j < 8; ++j) {
        const f32x4 bias4 = *(const f32x4*)&bias[cb + j * 4];
        const f32x4 g4 = *(const f32x4*)&bng[cb + j * 4];
        const f32x4 bb4 = *(const f32x4*)&bnb[cb + j * 4];
        f32x4 o = *(f32x4*)&O[(size_t)row * N + cb + j * 4];
#pragma unroll
        for (int e = 0; e < 4; ++e)
          o[e] += gelu_exact((v[j][e] + bias4[e]) * (g4[e] * RSQ) + bb4[e]);
        *(f32x4*)&O[(size_t)row * N + cb + j * 4] = o;
      }
    }
  }
}

// ---------------------------------------------------------------------------
// MFMA attention: one block per window (4 waves), one head per wave
// (head = blockIdx.y*4 + wave, grid y = 3). QK^T: 16 MFMAs, fragments
// loaded straight from the bf16 qkv chunk. Bias+mask in-register,
// softmax via shfl_xor over the 16-lane column groups. P -> bf16 per-wave
// LDS tile [64][72]. PV as O^T = V^T * P^T. No barriers (per-wave LDS).
// ---------------------------------------------------------------------------
__global__ __launch_bounds__(256) void attn_kernel(
    const unsigned short* __restrict__ qkv, const float* __restrict__ rpb,
    unsigned short* __restrict__ ao) {
  __shared__ __align__(16) unsigned short Pl[4][64 * 72];
  __shared__ float Inv[4][64];
  const int wloc = blockIdx.x;  // window within chunk (0..255)
  const int wave = threadIdx.x >> 6;
  const int lane = threadIdx.x & 63;
  const int head = blockIdx.y * 4 + wave;
  const int ln16 = lane & 15, qd = lane >> 4;
  const int wpos = wloc & 63;  // window position in image
  const int wh = (wpos >> 3) & 7, ww = wpos & 7;
  const unsigned short* qb = qkv + (size_t)wloc * 64 * 1152 + head * 32;

  // Q (A-operand) and K (B-operand) fragments: 16B per lane per tile.
  short8 aq[4], bk[4];
#pragma unroll
  for (int t = 0; t < 4; ++t) {
    aq[t] = *(const short8*)(qb + (size_t)(t * 16 + ln16) * 1152 + qd * 8);
    bk[t] = *(const short8*)(qb + (size_t)(t * 16 + ln16) * 1152 + 384 + qd * 8);
  }
  // V^T fragments for PV (A-operand of O^T = V^T P^T): issue early so the
  // u16 gathers overlap the QK MFMAs + softmax.
  short8 av[2][2];
#pragma unroll
  for (int dt = 0; dt < 2; ++dt)
#pragma unroll
    for (int ks = 0; ks < 2; ++ks)
#pragma unroll
      for (int j = 0; j < 8; ++j)
        av[dt][ks][j] = (short)qb[(size_t)(ks * 32 + qd * 8 + j) * 1152 + 768 +
                                  dt * 16 + ln16];

  f32x4 accS[4][4];
#pragma unroll
  for (int i = 0; i < 4; ++i)
#pragma unroll
    for (int j = 0; j < 4; ++j) accS[i][j] = (f32x4){0.f, 0.f, 0.f, 0.f};
#pragma unroll
  for (int mt = 0; mt < 4; ++mt)
#pragma unroll
    for (int nt = 0; nt < 4; ++nt)
      accS[mt][nt] = __builtin_amdgcn_mfma_f32_16x16x32_bf16(
          aq[mt], bk[nt], accS[mt][nt], 0, 0, 0);

  // Column-side (K-token) bias index + region label, per nt tile.
  int cmv[4], rlm[4];
#pragma unroll
  for (int nt = 0; nt < 4; ++nt) {
    const int m = nt * 16 + ln16;
    const int mf = 63 - m;
    cmv[nt] = 15 * (mf >> 3) + (mf & 7);
    rlm[nt] =
        region_label(wh * 8 + (m >> 3)) * 3 + region_label(ww * 8 + (m & 7));
  }
  const float scale = 0.17677669529663687f;  // 32^-0.5
  unsigned short* pw = &Pl[wave][0];
#pragma unroll
  for (int mt = 0; mt < 4; ++mt) {
#pragma unroll
    for (int rg = 0; rg < 4; ++rg) {
      const int n = mt * 16 + qd * 4 + rg;  // Q token (S row)
      const int cn = 15 * (n >> 3) + (n & 7);
      const int rln =
          region_label(wh * 8 + (n >> 3)) * 3 + region_label(ww * 8 + (n & 7));
      float vv[4];
#pragma unroll
      for (int nt = 0; nt < 4; ++nt) {
        float sv = accS[mt][nt][rg] * scale + rpb[(cn + cmv[nt]) * 12 + head];
        if (rln != rlm[nt]) sv -= 100.f;
        vv[nt] = sv;
      }
      float mx = fmaxf(fmaxf(vv[0], vv[1]), fmaxf(vv[2], vv[3]));
      mx = fmaxf(mx, __shfl_xor(mx, 1));
      mx = fmaxf(mx, __shfl_xor(mx, 2));
      mx = fmaxf(mx, __shfl_xor(mx, 4));
      mx = fmaxf(mx, __shfl_xor(mx, 8));
      float sum = 0.f;
#pragma unroll
      for (int nt = 0; nt < 4; ++nt) {
        vv[nt] = __expf(vv[nt] - mx);
        sum += vv[nt];
      }
      sum += __shfl_xor(sum, 1);
      sum += __shfl_xor(sum, 2);
      sum += __shfl_xor(sum, 4);
      sum += __shfl_xor(sum, 8);
      if (ln16 == 0) Inv[wave][n] = 1.0f / sum;
#pragma unroll
      for (int nt = 0; nt < 4; ++nt)
        pw[n * 72 + nt * 16 + ln16] = f2bf(vv[nt]);
    }
  }

  // PV: O^T = V^T * P^T. P^T B-fragments are contiguous b128 reads of Pl.
  f32x4 accO[2][4];
#pragma unroll
  for (int i = 0; i < 2; ++i)
#pragma unroll
    for (int j = 0; j < 4; ++j) accO[i][j] = (f32x4){0.f, 0.f, 0.f, 0.f};
#pragma unroll
  for (int ks = 0; ks < 2; ++ks) {
    short8 pb[4];
#pragma unroll
    for (int ntile = 0; ntile < 4; ++ntile)
      pb[ntile] =
          *(const short8*)&pw[(ntile * 16 + ln16) * 72 + ks * 32 + qd * 8];
#pragma unroll
    for (int dt = 0; dt < 2; ++dt)
#pragma unroll
      for (int ntile = 0; ntile < 4; ++ntile)
        accO[dt][ntile] = __builtin_amdgcn_mfma_f32_16x16x32_bf16(
            av[dt][ks], pb[ntile], accO[dt][ntile], 0, 0, 0);
  }

  float invn[4];
#pragma unroll
  for (int ntile = 0; ntile < 4; ++ntile)
    invn[ntile] = Inv[wave][ntile * 16 + ln16];
#pragma unroll
  for (int dt = 0; dt < 2; ++dt) {
#pragma unroll
    for (int ntile = 0; ntile < 4; ++ntile) {
      const int tok = ntile * 16 + ln16;
      const int d0 = dt * 16 + qd * 4;
      uint2 st;
      st.x = (unsigned)f2bf(accO[dt][ntile][0] * invn[ntile]) |
             ((unsigned)f2bf(accO[dt][ntile][1] * invn[ntile]) << 16);
      st.y = (unsigned)f2bf(accO[dt][ntile][2] * invn[ntile]) |
             ((unsigned)f2bf(accO[dt][ntile][3] * invn[ntile]) << 16);
      *(uint2*)&ao[((size_t)wloc * 64 + tok) * CCH + head * 32 + d0] = st;
    }
  }
}

// ---------------------------------------------------------------------------
// Depthwise 3x3 SAME + bias + BN2 + GELU, bf16 in/out, 8 channels/thread.
// dwt is [tap][1536] fp32. Grid covers 16384 pixels x 192 channel-groups.
// ---------------------------------------------------------------------------
__global__ __launch_bounds__(256) void dw_kernel(
    const unsigned short* __restrict__ z1, const float* __restrict__ dwt,
    const float* __restrict__ dwb, const float* __restrict__ bn2g,
    const float* __restrict__ bn2b, unsigned short* __restrict__ z2) {
  const int g = blockIdx.x * 256 + threadIdx.x;  // 0..3145727
  const int pix = g / 192;
  const int cg = g - pix * 192;
  const int c0 = cg * 8;
  const int p = pix & 4095;
  const int h = p >> 6, w = p & 63;
  const unsigned short* zb = z1 + (size_t)(pix >> 12) * 4096 * HIDCH;

  float a[8];
  {
    const float4 b0 = *(const float4*)&dwb[c0];
    const float4 b1 = *(const float4*)&dwb[c0 + 4];
    a[0] = b0.x; a[1] = b0.y; a[2] = b0.z; a[3] = b0.w;
    a[4] = b1.x; a[5] = b1.y; a[6] = b1.z; a[7] = b1.w;
  }
#pragma unroll
  for (int dh = -1; dh <= 1; ++dh) {
    const int hh = h + dh;
    if (hh < 0 || hh > 63) continue;
#pragma unroll
    for (int dx = -1; dx <= 1; ++dx) {
      const int wn = w + dx;
      if (wn < 0 || wn > 63) continue;
      const int tap = (dh + 1) * 3 + (dx + 1);
      const int4 zv = *(const int4*)&zb[((size_t)hh * 64 + wn) * HIDCH + c0];
      const float* wp = &dwt[tap * HIDCH + c0];
      const float4 w0 = *(const float4*)wp;
      const float4 w1 = *(const float4*)(wp + 4);
      a[0] += bf2f((unsigned short)(zv.x & 0xFFFF)) * w0.x;
      a[1] += bf2f((unsigned short)(((unsigned)zv.x) >> 16)) * w0.y;
      a[2] += bf2f((unsigned short)(zv.y & 0xFFFF)) * w0.z;
      a[3] += bf2f((unsigned short)(((unsigned)zv.y) >> 16)) * w0.w;
      a[4] += bf2f((unsigned short)(zv.z & 0xFFFF)) * w1.x;
      a[5] += bf2f((unsigned short)(((unsigned)zv.z) >> 16)) * w1.y;
      a[6] += bf2f((unsigned short)(zv.w & 0xFFFF)) * w1.z;
      a[7] += bf2f((unsigned short)(((unsigned)zv.w) >> 16)) * w1.w;
    }
  }
  const float RSQ = 0.99999500003749969f;
  const float4 g0 = *(const float4*)&bn2g[c0];
  const float4 g1 = *(const float4*)&bn2g[c0 + 4];
  const float4 bb0 = *(const float4*)&bn2b[c0];
  const float4 bb1 = *(const float4*)&bn2b[c0 + 4];
  const float gs[8] = {g0.x, g0.y, g0.z, g0.w, g1.x, g1.y, g1.z, g1.w};
  const float bs[8] = {bb0.x, bb0.y, bb0.z, bb0.w, bb1.x, bb1.y, bb1.z, bb1.w};
  unsigned pk[4];
#pragma unroll
  for (int i = 0; i < 4; ++i) {
    const float v0 = gelu_exact(a[2 * i] * (gs[2 * i] * RSQ) + bs[2 * i]);
    const float v1 =
        gelu_exact(a[2 * i + 1] * (gs[2 * i + 1] * RSQ) + bs[2 * i + 1]);
    pk[i] = (unsigned)f2bf(v0) | ((unsigned)f2bf(v1) << 16);
  }
  int4 st;
  st.x = pk[0]; st.y = pk[1]; st.z = pk[2]; st.w = pk[3];
  *(int4*)&z2[(size_t)pix * HIDCH + c0] = st;
}

extern "C" void kernel_launch(void* const* d_in, const int* in_sizes, int n_in,
                              void* d_out, int out_size, void* d_ws,
                              size_t ws_size, hipStream_t stream) {
  const float* x = (const float*)d_in[0];
  const float* ln1_g = (const float*)d_in[3];
  const float* ln1_b = (const float*)d_in[4];
  const float* qkv_w = (const float*)d_in[5];
  const float* qkv_b = (const float*)d_in[6];
  const float* rpb = (const float*)d_in[7];
  const float* proj_w = (const float*)d_in[8];
  const float* proj_b = (const float*)d_in[9];
  const float* ln2_g = (const float*)d_in[10];
  const float* ln2_b = (const float*)d_in[11];
  const float* fc1_w = (const float*)d_in[12];
  const float* fc1_b = (const float*)d_in[13];
  const float* bn1_g = (const float*)d_in[14];
  const float* bn1_b = (const float*)d_in[15];
  const float* dw_w = (const float*)d_in[16];
  const float* dw_b = (const float*)d_in[17];
  const float* bn2_g = (const float*)d_in[18];
  const float* bn2_b = (const float*)d_in[19];
  const float* fc2_w = (const float*)d_in[20];
  const float* fc2_b = (const float*)d_in[21];
  const float* bn3_g = (const float*)d_in[22];
  const float* bn3_b = (const float*)d_in[23];
  float* out = (float*)d_out;

  char* ws = (char*)d_ws;
  unsigned short* wsA = (unsigned short*)ws;                // 50.3 MB
  unsigned short* wsAO = (unsigned short*)(ws + 50331648);  // 50.3 MB
  unsigned short* wsQ = (unsigned short*)(ws + 100663296);  // 50.3 MB
  unsigned short* wbf = (unsigned short*)(ws + 150994944);  // 3.5 MB
  float* dwt = (float*)(ws + 154533888);                    // 55 KB
  unsigned short* w_qkv = wbf;
  unsigned short* w_proj = wbf + 442368;
  unsigned short* w_fc1 = wbf + 589824;
  unsigned short* w_fc2 = wbf + 1179648;

  // 0. weights -> bf16 (+ dw transpose to fp32 [9][1536])
  convw_kernel<<<6966, 256, 0, stream>>>(qkv_w, proj_w, fc1_w, fc2_w, dw_w,
                                         wbf, dwt);
  // 1. LN1 + roll + window partition (4 tokens/block, wave per token)
  ln_kernel<1><<<16384, 256, 0, stream>>>(x, ln1_g, ln1_b, wsA);
  // 2. QKV GEMM + attention per 4-batch chunk (16384 tokens)
  for (int cb = 0; cb < 4; ++cb) {
    mfma_gemm<0><<<dim3(128, 9), 256, 0, stream>>>(
        wsA + (size_t)cb * 16384 * CCH, w_qkv, qkv_b, wsQ, nullptr, nullptr,
        nullptr, 1152, CCH);
    attn_kernel<<<dim3(256, 3), 256, 0, stream>>>(
        wsQ, rpb, wsAO + (size_t)cb * 16384 * CCH);
  }
  // 3. proj + unwindow + unroll + residual -> d_out
  mfma_gemm<1><<<dim3(512, 3), 256, 0, stream>>>(wsAO, w_proj, proj_b, out, x,
                                                 nullptr, nullptr, CCH, CCH);
  // 4. LN2 -> wsA
  ln_kernel<0><<<16384, 256, 0, stream>>>(out, ln2_g, ln2_b, wsA);
  // 5. MLP per 4-batch chunk; z1 = wsAO, z2 = wsQ
  for (int cb = 0; cb < 4; ++cb) {
    mfma_gemm<2><<<dim3(128, 12), 256, 0, stream>>>(
        wsA + (size_t)cb * 16384 * CCH, w_fc1, fc1_b, wsAO, nullptr, bn1_g,
        bn1_b, HIDCH, CCH);
    dw_kernel<<<12288, 256, 0, stream>>>(wsAO, dwt, dw_b, bn2_g, bn2_b, wsQ);
    mfma_gemm<3><<<dim3(128, 3), 256, 0, stream>>>(
        wsQ, w_fc2, fc2_b, out + (size_t)cb * 16384 * CCH, nullptr, bn3_g,
        bn3_b, CCH, HIDCH);
  }
}

// Round 5
// 1071.413 us; speedup vs baseline: 1.1338x; 1.1338x over previous
//
#include <hip/hip_runtime.h>
#include <cstddef>

// Swin shifted-window block, bf16-MFMA version, round 7.
// Post-mortem r4: LDS-staged epilogue REGRESSED (75->86us, conflicts back)
//   -> reverted to direct fragment stores (round-3 form, proven 75us).
// Theory: GEMMs are occupancy/latency-bound (18% occ, 3 TB/s, nothing
// saturated). Changes vs round 3:
//  - mfma_gemm: 512 threads / 8 waves, 64x32 per wave -> acc 32 AGPR
//    (was 64), ~halved register footprint per wave => ~2x resident waves.
//    Staging: ONE global_load_lds per operand per K-step (512 thr x 16B
//    = full 8KB half-tile), 2-deep pipeline, counted vmcnt(2), same XOR
//    chunk swizzle (re-verified conflict-free for new layout).
//  - T1 XCD swizzle on linearized block id (all grids %8==0; guarded).
//
// ws layout (bytes):
//   [0,           50331648)   wsA   : LN1 out / LN2 out (bf16)
//   [50331648,   100663296)   wsAO  : attn out / z1 (bf16)
//   [100663296,  150994944)   wsQ   : qkv chunk / z2 (bf16)
//   [150994944,  154533888)   wbf   : bf16 weights
//   [154533888,  154589184)   dwt   : fp32 dw weights [9][1536]
// peak ~147.4 MiB.

#define CCH 384
#define HIDCH 1536

typedef __attribute__((ext_vector_type(8))) short short8;
typedef __attribute__((ext_vector_type(4))) float f32x4;

__device__ __forceinline__ float gelu_exact(float v) {
  return 0.5f * v * (1.0f + erff(v * 0.70710678118654752440f));
}
__device__ __forceinline__ unsigned short f2bf(float f) {
  unsigned u = __builtin_bit_cast(unsigned, f);
  u = (u + 0x7FFF + ((u >> 16) & 1)) >> 16;
  return (unsigned short)u;
}
__device__ __forceinline__ float bf2f(unsigned short s) {
  return __builtin_bit_cast(float, (unsigned)s << 16);
}
__device__ __forceinline__ int region_label(int p) {
  return (p < 56) ? 0 : ((p < 60) ? 1 : 2);
}

// async global->LDS, 16B per lane. LDS dest = wave-uniform base + lane*16.
__device__ __forceinline__ void gl_lds16(const void* g, void* l) {
  __builtin_amdgcn_global_load_lds(
      (const __attribute__((address_space(1))) unsigned int*)g,
      (__attribute__((address_space(3))) unsigned int*)l, 16, 0, 0);
}

// ---------------------------------------------------------------------------
// Weight prep: fp32->bf16 for qkv/proj/fc1/fc2, plus dw transpose to
// dwt[tap*1536 + c] = dw_w[c*9 + tap] (fp32).
// ---------------------------------------------------------------------------
__global__ __launch_bounds__(256) void convw_kernel(
    const float* __restrict__ a, const float* __restrict__ b,
    const float* __restrict__ c, const float* __restrict__ d,
    const float* __restrict__ dww, unsigned short* __restrict__ o,
    float* __restrict__ dwt) {
  const int i = blockIdx.x * 256 + threadIdx.x;
  // 442368 + 147456 + 589824 + 589824 = 1769472 bf16 weights, then 13824 dwt
  if (i < 1769472) {
    float v;
    if (i < 442368) v = a[i];
    else if (i < 589824) v = b[i - 442368];
    else if (i < 1179648) v = c[i - 589824];
    else v = d[i - 1179648];
    o[i] = f2bf(v);
  } else if (i < 1769472 + 13824) {
    const int j = i - 1769472;
    const int tap = j / 1536;
    const int ch = j - tap * 1536;
    dwt[j] = dww[ch * 9 + tap];
  }
}

// ---------------------------------------------------------------------------
// LayerNorm -> bf16, one wave per token, 6 channels per lane (float2 x3).
// REMAP=1: out token is windowed/rolled; src via roll(+4).
// ---------------------------------------------------------------------------
template <int REMAP>
__global__ __launch_bounds__(256) void ln_kernel(const float* __restrict__ x,
                                                 const float* __restrict__ g,
                                                 const float* __restrict__ b,
                                                 unsigned short* __restrict__ y) {
  const int t = blockIdx.x * 4 + (threadIdx.x >> 6);
  const int lane = threadIdx.x & 63;
  size_t src;
  if (REMAP) {
    const int widx = t >> 6;
    const int n = t & 63;
    const int bb = widx >> 6;
    const int wh = (widx >> 3) & 7;
    const int ww = widx & 7;
    const int hp = wh * 8 + (n >> 3);
    const int wp = ww * 8 + (n & 7);
    const int hs = (hp + 4) & 63;
    const int wsrc = (wp + 4) & 63;
    src = (size_t)bb * 4096 + hs * 64 + wsrc;
  } else {
    src = (size_t)t;
  }
  const float* xr = x + src * CCH + lane * 6;
  const float2 p0 = *(const float2*)xr;
  const float2 p1 = *(const float2*)(xr + 2);
  const float2 p2 = *(const float2*)(xr + 4);
  float v[6] = {p0.x, p0.y, p1.x, p1.y, p2.x, p2.y};
  float s = 0.f, s2 = 0.f;
#pragma unroll
  for (int j = 0; j < 6; ++j) {
    s += v[j];
    s2 += v[j] * v[j];
  }
#pragma unroll
  for (int o = 1; o < 64; o <<= 1) {
    s += __shfl_xor(s, o);
    s2 += __shfl_xor(s2, o);
  }
  const float mean = s * (1.0f / 384.0f);
  const float var = s2 * (1.0f / 384.0f) - mean * mean;
  const float rstd = rsqrtf(var + 1e-5f);
  const float2 g0 = *(const float2*)(g + lane * 6);
  const float2 g1 = *(const float2*)(g + lane * 6 + 2);
  const float2 g2 = *(const float2*)(g + lane * 6 + 4);
  const float2 b0 = *(const float2*)(b + lane * 6);
  const float2 b1 = *(const float2*)(b + lane * 6 + 2);
  const float2 b2 = *(const float2*)(b + lane * 6 + 4);
  const float gg[6] = {g0.x, g0.y, g1.x, g1.y, g2.x, g2.y};
  const float bv[6] = {b0.x, b0.y, b1.x, b1.y, b2.x, b2.y};
  unsigned pk[3];
#pragma unroll
  for (int i = 0; i < 3; ++i) {
    const float r0 = (v[2 * i] - mean) * rstd * gg[2 * i] + bv[2 * i];
    const float r1 = (v[2 * i + 1] - mean) * rstd * gg[2 * i + 1] + bv[2 * i + 1];
    pk[i] = (unsigned)f2bf(r0) | ((unsigned)f2bf(r1) << 16);
  }
  unsigned* yo = (unsigned*)(y + (size_t)t * CCH + lane * 6);
  yo[0] = pk[0];
  yo[1] = pk[1];
  yo[2] = pk[2];
}

// ---------------------------------------------------------------------------
// bf16 MFMA GEMM: C = A(MxK,bf16) @ W(NxK,bf16)^T + bias.
// 128x128 tile, 512 thr = 8 waves (2M x 4N), each wave 64x32 out
// (4x2 MFMA 16x16x32, acc = 32 AGPR). One global_load_lds per operand
// per K-step (512 thr x 16B = 8KB tile), 2-deep pipeline, vmcnt(2),
// XOR chunk swizzle. Direct fragment-store epilogue (round-3 form).
// T1 XCD swizzle on linearized block id.
// MODE 0: qkv  -> bf16 store (r*N+c)
// MODE 1: proj -> fp32, window-reverse+roll remap, Cout[dst] = Xres[dst]+val
// MODE 2: fc1  -> bf16, gelu(bn(val))
// MODE 3: fc2  -> fp32, Cout[r*N+c] += gelu(bn(val))
// ---------------------------------------------------------------------------
template <int MODE>
__global__ __launch_bounds__(512) void mfma_gemm(
    const unsigned short* __restrict__ A, const unsigned short* __restrict__ W,
    const float* __restrict__ bias, void* __restrict__ CoutV,
    const float* __restrict__ Xres, const float* __restrict__ bng,
    const float* __restrict__ bnb, int N, int K) {
  // A: [2][8192] at smem+0 ; B: [2][8192] at smem+16384
  __shared__ __align__(16) char smem[32768];
  const int tid = threadIdx.x;
  const int wave = tid >> 6, lane = tid & 63;
  const int qd = lane >> 4, ln16 = lane & 15;
  const int wm = wave >> 2, wn = wave & 3;

  // T1: XCD-aware swizzle of linearized block id (bijective when tot%8==0).
  const int nx = gridDim.x;
  const int lid0 = blockIdx.x + blockIdx.y * nx;
  const int tot = nx * gridDim.y;
  int lid = lid0;
  if ((tot & 7) == 0) lid = (lid0 & 7) * (tot >> 3) + (lid0 >> 3);
  const int m0 = (lid % nx) * 128;
  const int n0 = (lid / nx) * 128;

  f32x4 acc[4][2];
#pragma unroll
  for (int i = 0; i < 4; ++i)
#pragma unroll
    for (int j = 0; j < 2; ++j) acc[i][j] = (f32x4){0.f, 0.f, 0.f, 0.f};

  const int r = tid >> 2;  // 0..127, row within tile
  // swizzled 16B-chunk index: lane's chunk (tid&3) XOR (row>>1)&3
  const int cks = ((tid & 3) ^ ((tid >> 3) & 3)) * 8;

  const unsigned short* gA = A + (size_t)(m0 + r) * K + cks;
  const unsigned short* gB = W + (size_t)(n0 + r) * K + cks;
  char* baseA = smem;
  char* baseB = smem + 16384;
  const int wofs = wave * 1024;  // 64 lanes x 16B per wave

  const int ntk = K >> 5;
  // prologue: stage tile 0 into buffer 0
  gl_lds16(gA, baseA + wofs);
  gl_lds16(gB, baseB + wofs);

  // fragment-read slot (same XOR involution as staging side; row bits
  // 1..2 of all fragment rows equal ln16 bits 1..2).
  const int sA = (qd ^ ((ln16 >> 1) & 3)) * 8;

  int cur = 0;
  for (int t = 0; t < ntk; ++t) {
    __builtin_amdgcn_s_barrier();  // all waves done reading buf cur^1
    __builtin_amdgcn_sched_barrier(0);
    if (t + 1 < ntk) {
      const int k1 = (t + 1) * 32;
      const int nb = cur ^ 1;
      gl_lds16(gA + k1, baseA + nb * 8192 + wofs);
      gl_lds16(gB + k1, baseB + nb * 8192 + wofs);
      asm volatile("s_waitcnt vmcnt(2)" ::: "memory");  // tile t landed
    } else {
      asm volatile("s_waitcnt vmcnt(0)" ::: "memory");
    }
    __builtin_amdgcn_s_barrier();  // every wave's tile-t staging visible
    __builtin_amdgcn_sched_barrier(0);
    short8 af[4], bfr[2];
#pragma unroll
    for (int mt = 0; mt < 4; ++mt)
      af[mt] = *(const short8*)(baseA + cur * 8192 +
                                ((wm * 64 + mt * 16 + ln16) * 32 + sA) * 2);
#pragma unroll
    for (int nt2 = 0; nt2 < 2; ++nt2)
      bfr[nt2] = *(const short8*)(baseB + cur * 8192 +
                                  ((wn * 32 + nt2 * 16 + ln16) * 32 + sA) * 2);
#pragma unroll
    for (int mt = 0; mt < 4; ++mt)
#pragma unroll
      for (int nt2 = 0; nt2 < 2; ++nt2)
        acc[mt][nt2] = __builtin_amdgcn_mfma_f32_16x16x32_bf16(
            af[mt], bfr[nt2], acc[mt][nt2], 0, 0, 0);
    cur ^= 1;
  }

  // ---- direct fragment-store epilogue (round-3 form) ----
  const float RSQ = 0.99999500003749969f;  // 1/sqrt(1+1e-5)
#pragma unroll
  for (int mt = 0; mt < 4; ++mt) {
#pragma unroll
    for (int nt2 = 0; nt2 < 2; ++nt2) {
      const int col = n0 + wn * 32 + nt2 * 16 + ln16;
      const int rbase = m0 + wm * 64 + mt * 16 + qd * 4;
#pragma unroll
      for (int rg = 0; rg < 4; ++rg) {
        const int row = rbase + rg;
        const float val = acc[mt][nt2][rg] + bias[col];
        if (MODE == 0) {
          ((unsigned short*)CoutV)[(size_t)row * N + col] = f2bf(val);
        } else if (MODE == 1) {
          const int widx = row >> 6, n = row & 63;
          const int bb = widx >> 6, wh = (widx >> 3) & 7, wwi = widx & 7;
          const int hp = wh * 8 + (n >> 3), wp = wwi * 8 + (n & 7);
          const int hh = (hp + 4) & 63, wwp = (wp + 4) & 63;
          const size_t dst = ((size_t)bb * 4096 + hh * 64 + wwp) * CCH + col;
          ((float*)CoutV)[dst] = Xres[dst] + val;
        } else {
          const float vbn = val * (bng[col] * RSQ) + bnb[col];
          const float ge = gelu_exact(vbn);
          if (MODE == 2) {
            ((unsigned short*)CoutV)[(size_t)row * N + col] = f2bf(ge);
          } else {
            float* o = (float*)CoutV + (size_t)row * N + col;
            *o = *o + ge;
          }
        }
      }
    }
  }
}

// ---------------------------------------------------------------------------
// MFMA attention: one block per window (4 waves), one head per wave
// (head = blockIdx.y*4 + wave, grid y = 3). QK^T: 16 MFMAs, fragments
// loaded straight from the bf16 qkv chunk. Bias+mask in-register,
// softmax via shfl_xor over the 16-lane column groups. P -> bf16 per-wave
// LDS tile [64][72]. PV as O^T = V^T * P^T. No barriers (per-wave LDS).
// ---------------------------------------------------------------------------
__global__ __launch_bounds__(256) void attn_kernel(
    const unsigned short* __restrict__ qkv, const float* __restrict__ rpb,
    unsigned short* __restrict__ ao) {
  __shared__ __align__(16) unsigned short Pl[4][64 * 72];
  __shared__ float Inv[4][64];
  const int wloc = blockIdx.x;  // window within chunk (0..255)
  const int wave = threadIdx.x >> 6;
  const int lane = threadIdx.x & 63;
  const int head = blockIdx.y * 4 + wave;
  const int ln16 = lane & 15, qd = lane >> 4;
  const int wpos = wloc & 63;  // window position in image
  const int wh = (wpos >> 3) & 7, ww = wpos & 7;
  const unsigned short* qb = qkv + (size_t)wloc * 64 * 1152 + head * 32;

  // Q (A-operand) and K (B-operand) fragments: 16B per lane per tile.
  short8 aq[4], bk[4];
#pragma unroll
  for (int t = 0; t < 4; ++t) {
    aq[t] = *(const short8*)(qb + (size_t)(t * 16 + ln16) * 1152 + qd * 8);
    bk[t] = *(const short8*)(qb + (size_t)(t * 16 + ln16) * 1152 + 384 + qd * 8);
  }
  // V^T fragments for PV (A-operand of O^T = V^T P^T): issue early so the
  // u16 gathers overlap the QK MFMAs + softmax.
  short8 av[2][2];
#pragma unroll
  for (int dt = 0; dt < 2; ++dt)
#pragma unroll
    for (int ks = 0; ks < 2; ++ks)
#pragma unroll
      for (int j = 0; j < 8; ++j)
        av[dt][ks][j] = (short)qb[(size_t)(ks * 32 + qd * 8 + j) * 1152 + 768 +
                                  dt * 16 + ln16];

  f32x4 accS[4][4];
#pragma unroll
  for (int i = 0; i < 4; ++i)
#pragma unroll
    for (int j = 0; j < 4; ++j) accS[i][j] = (f32x4){0.f, 0.f, 0.f, 0.f};
#pragma unroll
  for (int mt = 0; mt < 4; ++mt)
#pragma unroll
    for (int nt = 0; nt < 4; ++nt)
      accS[mt][nt] = __builtin_amdgcn_mfma_f32_16x16x32_bf16(
          aq[mt], bk[nt], accS[mt][nt], 0, 0, 0);

  // Column-side (K-token) bias index + region label, per nt tile.
  int cmv[4], rlm[4];
#pragma unroll
  for (int nt = 0; nt < 4; ++nt) {
    const int m = nt * 16 + ln16;
    const int mf = 63 - m;
    cmv[nt] = 15 * (mf >> 3) + (mf & 7);
    rlm[nt] =
        region_label(wh * 8 + (m >> 3)) * 3 + region_label(ww * 8 + (m & 7));
  }
  const float scale = 0.17677669529663687f;  // 32^-0.5
  unsigned short* pw = &Pl[wave][0];
#pragma unroll
  for (int mt = 0; mt < 4; ++mt) {
#pragma unroll
    for (int rg = 0; rg < 4; ++rg) {
      const int n = mt * 16 + qd * 4 + rg;  // Q token (S row)
      const int cn = 15 * (n >> 3) + (n & 7);
      const int rln =
          region_label(wh * 8 + (n >> 3)) * 3 + region_label(ww * 8 + (n & 7));
      float vv[4];
#pragma unroll
      for (int nt = 0; nt < 4; ++nt) {
        float sv = accS[mt][nt][rg] * scale + rpb[(cn + cmv[nt]) * 12 + head];
        if (rln != rlm[nt]) sv -= 100.f;
        vv[nt] = sv;
      }
      float mx = fmaxf(fmaxf(vv[0], vv[1]), fmaxf(vv[2], vv[3]));
      mx = fmaxf(mx, __shfl_xor(mx, 1));
      mx = fmaxf(mx, __shfl_xor(mx, 2));
      mx = fmaxf(mx, __shfl_xor(mx, 4));
      mx = fmaxf(mx, __shfl_xor(mx, 8));
      float sum = 0.f;
#pragma unroll
      for (int nt = 0; nt < 4; ++nt) {
        vv[nt] = __expf(vv[nt] - mx);
        sum += vv[nt];
      }
      sum += __shfl_xor(sum, 1);
      sum += __shfl_xor(sum, 2);
      sum += __shfl_xor(sum, 4);
      sum += __shfl_xor(sum, 8);
      if (ln16 == 0) Inv[wave][n] = 1.0f / sum;
#pragma unroll
      for (int nt = 0; nt < 4; ++nt)
        pw[n * 72 + nt * 16 + ln16] = f2bf(vv[nt]);
    }
  }

  // PV: O^T = V^T * P^T. P^T B-fragments are contiguous b128 reads of Pl.
  f32x4 accO[2][4];
#pragma unroll
  for (int i = 0; i < 2; ++i)
#pragma unroll
    for (int j = 0; j < 4; ++j) accO[i][j] = (f32x4){0.f, 0.f, 0.f, 0.f};
#pragma unroll
  for (int ks = 0; ks < 2; ++ks) {
    short8 pb[4];
#pragma unroll
    for (int ntile = 0; ntile < 4; ++ntile)
      pb[ntile] =
          *(const short8*)&pw[(ntile * 16 + ln16) * 72 + ks * 32 + qd * 8];
#pragma unroll
    for (int dt = 0; dt < 2; ++dt)
#pragma unroll
      for (int ntile = 0; ntile < 4; ++ntile)
        accO[dt][ntile] = __builtin_amdgcn_mfma_f32_16x16x32_bf16(
            av[dt][ks], pb[ntile], accO[dt][ntile], 0, 0, 0);
  }

  float invn[4];
#pragma unroll
  for (int ntile = 0; ntile < 4; ++ntile)
    invn[ntile] = Inv[wave][ntile * 16 + ln16];
#pragma unroll
  for (int dt = 0; dt < 2; ++dt) {
#pragma unroll
    for (int ntile = 0; ntile < 4; ++ntile) {
      const int tok = ntile * 16 + ln16;
      const int d0 = dt * 16 + qd * 4;
      uint2 st;
      st.x = (unsigned)f2bf(accO[dt][ntile][0] * invn[ntile]) |
             ((unsigned)f2bf(accO[dt][ntile][1] * invn[ntile]) << 16);
      st.y = (unsigned)f2bf(accO[dt][ntile][2] * invn[ntile]) |
             ((unsigned)f2bf(accO[dt][ntile][3] * invn[ntile]) << 16);
      *(uint2*)&ao[((size_t)wloc * 64 + tok) * CCH + head * 32 + d0] = st;
    }
  }
}

// ---------------------------------------------------------------------------
// Depthwise 3x3 SAME + bias + BN2 + GELU, bf16 in/out, 8 channels/thread.
// dwt is [tap][1536] fp32. Grid covers 16384 pixels x 192 channel-groups.
// ---------------------------------------------------------------------------
__global__ __launch_bounds__(256) void dw_kernel(
    const unsigned short* __restrict__ z1, const float* __restrict__ dwt,
    const float* __restrict__ dwb, const float* __restrict__ bn2g,
    const float* __restrict__ bn2b, unsigned short* __restrict__ z2) {
  const int g = blockIdx.x * 256 + threadIdx.x;  // 0..3145727
  const int pix = g / 192;
  const int cg = g - pix * 192;
  const int c0 = cg * 8;
  const int p = pix & 4095;
  const int h = p >> 6, w = p & 63;
  const unsigned short* zb = z1 + (size_t)(pix >> 12) * 4096 * HIDCH;

  float a[8];
  {
    const float4 b0 = *(const float4*)&dwb[c0];
    const float4 b1 = *(const float4*)&dwb[c0 + 4];
    a[0] = b0.x; a[1] = b0.y; a[2] = b0.z; a[3] = b0.w;
    a[4] = b1.x; a[5] = b1.y; a[6] = b1.z; a[7] = b1.w;
  }
#pragma unroll
  for (int dh = -1; dh <= 1; ++dh) {
    const int hh = h + dh;
    if (hh < 0 || hh > 63) continue;
#pragma unroll
    for (int dx = -1; dx <= 1; ++dx) {
      const int wn = w + dx;
      if (wn < 0 || wn > 63) continue;
      const int tap = (dh + 1) * 3 + (dx + 1);
      const int4 zv = *(const int4*)&zb[((size_t)hh * 64 + wn) * HIDCH + c0];
      const float* wp = &dwt[tap * HIDCH + c0];
      const float4 w0 = *(const float4*)wp;
      const float4 w1 = *(const float4*)(wp + 4);
      a[0] += bf2f((unsigned short)(zv.x & 0xFFFF)) * w0.x;
      a[1] += bf2f((unsigned short)(((unsigned)zv.x) >> 16)) * w0.y;
      a[2] += bf2f((unsigned short)(zv.y & 0xFFFF)) * w0.z;
      a[3] += bf2f((unsigned short)(((unsigned)zv.y) >> 16)) * w0.w;
      a[4] += bf2f((unsigned short)(zv.z & 0xFFFF)) * w1.x;
      a[5] += bf2f((unsigned short)(((unsigned)zv.z) >> 16)) * w1.y;
      a[6] += bf2f((unsigned short)(zv.w & 0xFFFF)) * w1.z;
      a[7] += bf2f((unsigned short)(((unsigned)zv.w) >> 16)) * w1.w;
    }
  }
  const float RSQ = 0.99999500003749969f;
  const float4 g0 = *(const float4*)&bn2g[c0];
  const float4 g1 = *(const float4*)&bn2g[c0 + 4];
  const float4 bb0 = *(const float4*)&bn2b[c0];
  const float4 bb1 = *(const float4*)&bn2b[c0 + 4];
  const float gs[8] = {g0.x, g0.y, g0.z, g0.w, g1.x, g1.y, g1.z, g1.w};
  const float bs[8] = {bb0.x, bb0.y, bb0.z, bb0.w, bb1.x, bb1.y, bb1.z, bb1.w};
  unsigned pk[4];
#pragma unroll
  for (int i = 0; i < 4; ++i) {
    const float v0 = gelu_exact(a[2 * i] * (gs[2 * i] * RSQ) + bs[2 * i]);
    const float v1 =
        gelu_exact(a[2 * i + 1] * (gs[2 * i + 1] * RSQ) + bs[2 * i + 1]);
    pk[i] = (unsigned)f2bf(v0) | ((unsigned)f2bf(v1) << 16);
  }
  int4 st;
  st.x = pk[0]; st.y = pk[1]; st.z = pk[2]; st.w = pk[3];
  *(int4*)&z2[(size_t)pix * HIDCH + c0] = st;
}

extern "C" void kernel_launch(void* const* d_in, const int* in_sizes, int n_in,
                              void* d_out, int out_size, void* d_ws,
                              size_t ws_size, hipStream_t stream) {
  const float* x = (const float*)d_in[0];
  const float* ln1_g = (const float*)d_in[3];
  const float* ln1_b = (const float*)d_in[4];
  const float* qkv_w = (const float*)d_in[5];
  const float* qkv_b = (const float*)d_in[6];
  const float* rpb = (const float*)d_in[7];
  const float* proj_w = (const float*)d_in[8];
  const float* proj_b = (const float*)d_in[9];
  const float* ln2_g = (const float*)d_in[10];
  const float* ln2_b = (const float*)d_in[11];
  const float* fc1_w = (const float*)d_in[12];
  const float* fc1_b = (const float*)d_in[13];
  const float* bn1_g = (const float*)d_in[14];
  const float* bn1_b = (const float*)d_in[15];
  const float* dw_w = (const float*)d_in[16];
  const float* dw_b = (const float*)d_in[17];
  const float* bn2_g = (const float*)d_in[18];
  const float* bn2_b = (const float*)d_in[19];
  const float* fc2_w = (const float*)d_in[20];
  const float* fc2_b = (const float*)d_in[21];
  const float* bn3_g = (const float*)d_in[22];
  const float* bn3_b = (const float*)d_in[23];
  float* out = (float*)d_out;

  char* ws = (char*)d_ws;
  unsigned short* wsA = (unsigned short*)ws;                // 50.3 MB
  unsigned short* wsAO = (unsigned short*)(ws + 50331648);  // 50.3 MB
  unsigned short* wsQ = (unsigned short*)(ws + 100663296);  // 50.3 MB
  unsigned short* wbf = (unsigned short*)(ws + 150994944);  // 3.5 MB
  float* dwt = (float*)(ws + 154533888);                    // 55 KB
  unsigned short* w_qkv = wbf;
  unsigned short* w_proj = wbf + 442368;
  unsigned short* w_fc1 = wbf + 589824;
  unsigned short* w_fc2 = wbf + 1179648;

  // 0. weights -> bf16 (+ dw transpose to fp32 [9][1536])
  convw_kernel<<<6966, 256, 0, stream>>>(qkv_w, proj_w, fc1_w, fc2_w, dw_w,
                                         wbf, dwt);
  // 1. LN1 + roll + window partition (4 tokens/block, wave per token)
  ln_kernel<1><<<16384, 256, 0, stream>>>(x, ln1_g, ln1_b, wsA);
  // 2. QKV GEMM + attention per 4-batch chunk (16384 tokens)
  for (int cb = 0; cb < 4; ++cb) {
    mfma_gemm<0><<<dim3(128, 9), 512, 0, stream>>>(
        wsA + (size_t)cb * 16384 * CCH, w_qkv, qkv_b, wsQ, nullptr, nullptr,
        nullptr, 1152, CCH);
    attn_kernel<<<dim3(256, 3), 256, 0, stream>>>(
        wsQ, rpb, wsAO + (size_t)cb * 16384 * CCH);
  }
  // 3. proj + unwindow + unroll + residual -> d_out
  mfma_gemm<1><<<dim3(512, 3), 512, 0, stream>>>(wsAO, w_proj, proj_b, out, x,
                                                 nullptr, nullptr, CCH, CCH);
  // 4. LN2 -> wsA
  ln_kernel<0><<<16384, 256, 0, stream>>>(out, ln2_g, ln2_b, wsA);
  // 5. MLP per 4-batch chunk; z1 = wsAO, z2 = wsQ
  for (int cb = 0; cb < 4; ++cb) {
    mfma_gemm<2><<<dim3(128, 12), 512, 0, stream>>>(
        wsA + (size_t)cb * 16384 * CCH, w_fc1, fc1_b, wsAO, nullptr, bn1_g,
        bn1_b, HIDCH, CCH);
    dw_kernel<<<12288, 256, 0, stream>>>(wsAO, dwt, dw_b, bn2_g, bn2_b, wsQ);
    mfma_gemm<3><<<dim3(128, 3), 512, 0, stream>>>(
        wsQ, w_fc2, fc2_b, out + (size_t)cb * 16384 * CCH, nullptr, bn3_g,
        bn3_b, CCH, HIDCH);
  }
}